// Round 6
// baseline (168.063 us; speedup 1.0000x reference)
//
#include <hip/hip_runtime.h>
#include <hip/hip_bf16.h>

#define BH 120
#define BW 240
#define NLVL 5
#define NCAM 6
#define CH 128
#define FH 64
#define FW 176
#define CIN 655
#define CINP 672            // padded to 21*32
#define NCT 21
#define FROWS 124           // padded rows; 0..121 used, 122..123 slack
#define FCOLS 242
#define NPIX (BH*BW)

typedef __hip_bfloat16 bf16;
typedef __attribute__((ext_vector_type(8))) short s16x8;
typedef __attribute__((ext_vector_type(4))) float f32x4;
typedef unsigned int uint;
typedef __attribute__((ext_vector_type(4), aligned(4))) uint uint4a;

#define G_AS __attribute__((address_space(1)))
#define L_AS __attribute__((address_space(3)))

__device__ __forceinline__ float bf2f(unsigned short u) {
    union { unsigned int i; float f; } c; c.i = ((unsigned int)u) << 16; return c.f;
}
__device__ __forceinline__ uint f2bu(float x) {
    return (uint)__hip_bfloat16_raw(__float2bfloat16(x)).x;
}
__device__ __forceinline__ float blo(uint u) {
    union { uint i; float f; } c; c.i = u << 16; return c.f;
}
__device__ __forceinline__ float bhi(uint u) {
    union { uint i; float f; } c; c.i = u & 0xFFFF0000u; return c.f;
}

// ---------------------------------------------------------------------------
// Kernel T: transpose cam_feat [6][128][64][176] f32 -> camt bf16 [6][64][176][128]
// ---------------------------------------------------------------------------
__global__ __launch_bounds__(256) void transpose_kernel(
    const float* __restrict__ in, bf16* __restrict__ out)
{
    __shared__ float t[32][129];
    int n = blockIdx.z, h = blockIdx.y, w0 = blockIdx.x * 32;
    int wlim = min(32, FW - w0);
    int wx = threadIdx.x & 31, cg = threadIdx.x >> 5;
    if (wx < wlim) {
        #pragma unroll
        for (int k = 0; k < 16; ++k) {
            int c = cg + k * 8;
            t[wx][c] = in[((n*CH + c)*FH + h)*FW + w0 + wx];
        }
    }
    __syncthreads();
    int c2 = threadIdx.x & 127, wi = threadIdx.x >> 7;
    for (int w = wi; w < wlim; w += 2)
        out[((n*FH + h)*FW + w0 + w)*CH + c2] = __float2bfloat16(t[w][c2]);
}

// ---------------------------------------------------------------------------
// Kernel W: conv_w [128][655][3][3] f32 -> wbf [9][128][672] bf16 (tail zero)
// ---------------------------------------------------------------------------
__global__ __launch_bounds__(256) void wprep_kernel(
    const float* __restrict__ w, bf16* __restrict__ wbf)
{
    int idx = blockIdx.x * 256 + threadIdx.x;
    if (idx >= 128 * CINP) return;
    int oc = idx / CINP, cin = idx - oc * CINP;
    float v[9];
    if (cin < CIN) {
        const float* s = w + ((size_t)oc * CIN + cin) * 9;
        #pragma unroll
        for (int k = 0; k < 9; ++k) v[k] = s[k];
    } else {
        #pragma unroll
        for (int k = 0; k < 9; ++k) v[k] = 0.f;
    }
    #pragma unroll
    for (int k = 0; k < 9; ++k)
        wbf[(size_t)(k * 128 + oc) * CINP + cin] = __float2bfloat16(v[k]);
}

// ---------------------------------------------------------------------------
// Kernel Z: zero the 724 border pixels across all 672 cin.
// ---------------------------------------------------------------------------
__global__ __launch_bounds__(128) void border_kernel(bf16* __restrict__ feat)
{
    int b = blockIdx.x;            // 0..723
    int row, col;
    if (b < 242)      { row = 0;   col = b; }
    else if (b < 484) { row = 121; col = b - 242; }
    else if (b < 604) { row = b - 484 + 1; col = 0; }
    else              { row = b - 604 + 1; col = 241; }
    s16x8* p = (s16x8*)(feat + ((size_t)row*FCOLS + col)*CINP);
    int t = threadIdx.x;
    if (t < 84) p[t] = (s16x8){0,0,0,0,0,0,0,0};
}

// ---------------------------------------------------------------------------
// Kernel P v3: 1 wave = 1 BEV pixel; camt is bf16 (1 dword = 2ch per tap);
// XCD-swizzled blockIdx so each XCD owns a contiguous 15-row BEV slab
// (L2-local camt reuse). Weight precompute identical to v2 (verified).
// ---------------------------------------------------------------------------
__global__ __launch_bounds__(256) void proj_kernel(
    const bf16* __restrict__ camt,
    const float* __restrict__ e2c,
    const int* __restrict__ pimgh, const int* __restrict__ pimgw,
    bf16* __restrict__ feat)
{
    __shared__ int   s_soff[4][32];
    __shared__ float s_w4[4][30][4];
    __shared__ int   s_val[4][32];

    const int wv = threadIdx.x >> 6;
    const int lane = threadIdx.x & 63;
    const int bid = blockIdx.x;                      // 7200 blocks
    const int swz = (bid & 7) * 900 + (bid >> 3);    // T1 XCD swizzle
    const int pix = swz * 4 + wv;
    const int bx = pix % BW, by = pix / BW;
    float xw = (float)(-30.0 + bx * (60.0/239.0)); if (bx == BW-1) xw = 30.f;
    float yw = (float)(-15.0 + by * (30.0/119.0)); if (by == BH-1) yw = 15.f;

    const bool act = lane < 30;
    int valid = 0, ix = 0, iy = 0, cam = 0;
    float fx = 0.f, fy = 0.f;
    if (act) {
        int l = lane / 6; cam = lane - l*6;
        float h = -1.f + 0.5f * (float)l;
        const float* M = e2c + cam * 16;
        float cx = M[0]*xw + M[1]*yw + M[2]*h  + M[3];
        float cy = M[4]*xw + M[5]*yw + M[6]*h  + M[7];
        float cz = M[8]*xw + M[9]*yw + M[10]*h + M[11];
        float iw = (float)pimgw[0], ih = (float)pimgh[0];
        float px = ((cx/cz + 1e-9f)/iw - 0.5f) * 2.f;
        float py = ((cy/cz + 1e-9f)/ih - 0.5f) * 2.f;
        valid = (cz > 1e-9f) && (px > -1.f) && (px < 1.f)
                             && (py > -1.f) && (py < 1.f);
        float xs = ((px + 1.f)*(float)FW - 1.f) * 0.5f;
        float ys = ((py + 1.f)*(float)FH - 1.f) * 0.5f;
        float x0 = floorf(xs), y0 = floorf(ys);
        fx = xs - x0; fy = ys - y0;
        ix = (int)x0; iy = (int)y0;
        s_val[wv][lane] = valid;
    }
    __syncthreads();
    if (act) {
        int lbase = (lane / 6) * 6;
        int cnt = s_val[wv][lbase] + s_val[wv][lbase+1] + s_val[wv][lbase+2]
                + s_val[wv][lbase+3] + s_val[wv][lbase+4] + s_val[wv][lbase+5];
        float inv = (cnt > 0) ? (1.f / (float)cnt) : 0.f;
        float sc = valid ? inv : 0.f;
        int bx0 = min(max(ix, 0), FW-2);
        int by0 = min(max(iy, 0), FH-2);
        float gx0 = (1.f - fx) * sc, gx1 = fx * sc;
        float wx0 = 0.f, wx1 = 0.f;
        if (ix >= 0)     { if (ix == bx0) wx0 += gx0; else wx1 += gx0; }
        if (ix+1 <= FW-1){ if (ix+1 == bx0) wx0 += gx1; else wx1 += gx1; }
        float wy0 = 0.f, wy1 = 0.f;
        float gy0 = 1.f - fy, gy1 = fy;
        if (iy >= 0)     { if (iy == by0) wy0 += gy0; else wy1 += gy0; }
        if (iy+1 <= FH-1){ if (iy+1 == by0) wy0 += gy1; else wy1 += gy1; }
        s_w4[wv][lane][0] = wx0 * wy0;
        s_w4[wv][lane][1] = wx0 * wy1;
        s_w4[wv][lane][2] = wx1 * wy0;
        s_w4[wv][lane][3] = wx1 * wy1;
        s_soff[wv][lane] = valid ? ((cam*FH + by0)*FW + bx0)*CH : -1;
    }
    __syncthreads();

    const int c2 = lane * 2;
    float va[NLVL], vb[NLVL];
    #pragma unroll
    for (int l = 0; l < NLVL; ++l) { va[l] = 0.f; vb[l] = 0.f; }

    #pragma unroll
    for (int l = 0; l < NLVL; ++l) {
        #pragma unroll
        for (int cm = 0; cm < NCAM; ++cm) {
            int id = l*6 + cm;
            int so = s_soff[wv][id];
            if (so >= 0) {                       // wave-uniform branch
                const bf16* bp = camt + so + c2;
                uint q0 = *(const uint*)(bp);
                uint q2 = *(const uint*)(bp + CH);
                uint q1 = *(const uint*)(bp + FW*CH);
                uint q3 = *(const uint*)(bp + FW*CH + CH);
                float w0 = s_w4[wv][id][0], w1 = s_w4[wv][id][1];
                float w2 = s_w4[wv][id][2], w3 = s_w4[wv][id][3];
                va[l] += w0*blo(q0) + w1*blo(q1) + w2*blo(q2) + w3*blo(q3);
                vb[l] += w0*bhi(q0) + w1*bhi(q1) + w2*bhi(q2) + w3*bhi(q3);
            }
        }
    }

    bf16* dpix = feat + ((size_t)(by+1)*FCOLS + (bx+1))*CINP;
    uint u0 = f2bu(va[0]) | (f2bu(va[1]) << 16);
    uint u1 = f2bu(va[2]) | (f2bu(va[3]) << 16);
    uint u2 = f2bu(va[4]) | (f2bu(vb[0]) << 16);
    uint u3 = f2bu(vb[1]) | (f2bu(vb[2]) << 16);
    uint u4 = f2bu(vb[3]) | (f2bu(vb[4]) << 16);
    char* dst = (char*)(dpix + c2*5);
    *(uint4a*)dst = (uint4a){u0, u1, u2, u3};
    *(uint*)(dst + 16) = u4;
    if (lane < 15) {
        int j = lane / 5, l = lane - j*5;
        float v = (j == 0) ? xw : (j == 1) ? yw : (-1.f + 0.5f*(float)l);
        dpix[CH*5 + lane] = __float2bfloat16(v);
    }
}

// ---------------------------------------------------------------------------
// Kernel C v2: implicit-GEMM conv, K-split x4. Block = 128oc x (8x32)px,
// 4 waves, wave = 128oc x 64px (m=8, n=4 frags of 16x16x32).
// Weights: global->reg double-buffered (wbf is 1.7MB = L2-resident; each
// wave's 8 loads cover 16 full cachelines). Pixels: LDS halo double-buffer
// (22.5KB/buf), 1 barrier per ct (6/block vs 54 before).
// Per phase: 4 ds_read_b128 + 8 L2 loads + 32 MFMA -> MFMA-bound.
// ---------------------------------------------------------------------------
__global__ __launch_bounds__(256, 2) void conv_mfma_kernel(
    const bf16* __restrict__ feat,     // [124][242][672]
    const bf16* __restrict__ wbf,      // [9][128][672]
    bf16* __restrict__ part)           // [4][128][28800]
{
    __shared__ __align__(16) char lds[45056];       // 2 x 22528 halo buffers
    const int tid  = threadIdx.x;
    const int wv   = tid >> 6;
    const int lane = tid & 63;
    const int t15  = tid & 15;
    const int kgl  = (tid >> 4) & 3;
    const int y0p = blockIdx.y * 8;        // 15 row-tiles
    const int x0p = blockIdx.x * 32;       // 8 col-tiles (last clamped)
    const int q   = blockIdx.z;
    const int ct0 = q ? (1 + 5*q) : 0;     // 0,6,11,16
    const int nct = q ? 5 : 6;
    const int HBS = 22528;

    f32x4 acc[8][4];
    #pragma unroll
    for (int m = 0; m < 8; ++m)
        #pragma unroll
        for (int f = 0; f < 4; ++f)
            acc[m][f] = (f32x4){0.f, 0.f, 0.f, 0.f};

    // stage 10x34-pixel halo (rounded to 352 px) for cin-tile ct into buffer hb
    auto stageH = [&](int ct, int hb) {
        for (int j = wv; j < 22; j += 4) {
            int cch = j*64 + lane;               // 0..1407
            int pp = cch >> 2, kgp = cch & 3;    // halo pixel, k-group
            int kg = kgp ^ ((pp >> 1) & 3);      // source-side swizzle
            int row = pp / 34;
            int col = pp - row*34;
            int gc = min(x0p + col, FCOLS-1);    // col clamp for last tile
            const bf16* src = feat + ((size_t)(y0p + row)*FCOLS + gc)*CINP
                                   + ct*32 + kg*8;
            __builtin_amdgcn_global_load_lds((const G_AS void*)src,
                                             (L_AS void*)(lds + hb + j*1024),
                                             16, 0, 0);
        }
    };
    // weight fragments: 8 x 16B from L2 (oc = m*16+t15, k-slice kgl)
    auto loadA = [&](int ct, int off, s16x8* A) {
        const bf16* base = wbf + ((size_t)(off*128 + t15))*CINP + ct*32 + kgl*8;
        #pragma unroll
        for (int m = 0; m < 8; ++m)
            A[m] = *(const s16x8*)(base + (size_t)m*16*CINP);
    };

    s16x8 A0[8], A1[8];
    stageH(ct0, 0);
    loadA(ct0, 0, A0);
    __syncthreads();                 // drains vmcnt -> halo + A0 ready

    for (int c = 0; c < nct; ++c) {
        const int ct = ct0 + c;
        const int hb = (c & 1) ? HBS : 0;
        if (c + 1 < nct) stageH(ct + 1, (c & 1) ? 0 : HBS);
        #pragma unroll
        for (int off = 0; off < 9; ++off) {
            s16x8* Au = (off & 1) ? A1 : A0;     // static (loop unrolled)
            s16x8* Al = (off & 1) ? A0 : A1;
            if (off < 8)            loadA(ct, off + 1, Al);
            else if (c + 1 < nct)   loadA(ct + 1, 0, Al);
            const int ky = off / 3, kx = off - ky*3;
            #pragma unroll
            for (int f = 0; f < 4; ++f) {
                const int fr = f >> 1, fc = f & 1;
                int hp = (2*wv + fr + ky)*34 + fc*16 + t15 + kx;
                s16x8 Bv = *(const s16x8*)(lds + hb + hp*64
                                           + ((kgl ^ ((hp>>1)&3)) << 4));
                __builtin_amdgcn_s_setprio(1);
                #pragma unroll
                for (int m = 0; m < 8; ++m)
                    acc[m][f] = __builtin_amdgcn_mfma_f32_16x16x32_bf16(
                                    Au[m], Bv, acc[m][f], 0, 0, 0);
                __builtin_amdgcn_s_setprio(0);
            }
        }
        if (c + 1 < nct) {           // off=8 used A0, loaded next into A1
            #pragma unroll
            for (int m = 0; m < 8; ++m) A0[m] = A1[m];
        }
        __syncthreads();             // halo double-buffer handoff
    }

    bf16* pq = part + (size_t)q * (128*NPIX);
    #pragma unroll
    for (int f = 0; f < 4; ++f) {
        const int fr = f >> 1, fc = f & 1;
        const int x = x0p + fc*16 + t15;
        if (x < BW) {
            const int y = y0p + 2*wv + fr;
            #pragma unroll
            for (int m = 0; m < 8; ++m) {
                #pragma unroll
                for (int r = 0; r < 4; ++r) {
                    int oc = m*16 + kgl*4 + r;   // D: row=(lane>>4)*4+r
                    pq[(size_t)oc*NPIX + y*BW + x] = __float2bfloat16(acc[m][f][r]);
                }
            }
        }
    }
}

// ---------------------------------------------------------------------------
// Kernel R: out[oc][pix] = sum_q part[q][oc][pix] + bias[oc]
// ---------------------------------------------------------------------------
__global__ __launch_bounds__(256) void combine_kernel(
    const bf16* __restrict__ part, const float* __restrict__ bias,
    float* __restrict__ out)
{
    int i8 = blockIdx.x * 256 + threadIdx.x;
    if (i8 >= 128*NPIX/8) return;
    int oc = i8 / (NPIX/8);
    float s[8];
    float b = bias[oc];
    #pragma unroll
    for (int k = 0; k < 8; ++k) s[k] = b;
    #pragma unroll
    for (int qq = 0; qq < 4; ++qq) {
        s16x8 v = *(const s16x8*)(part + (size_t)qq*(128*NPIX) + (size_t)i8*8);
        #pragma unroll
        for (int k = 0; k < 8; ++k) s[k] += bf2f((unsigned short)v[k]);
    }
    f32x4* o = (f32x4*)(out + (size_t)i8*8);
    o[0] = (f32x4){s[0], s[1], s[2], s[3]};
    o[1] = (f32x4){s[4], s[5], s[6], s[7]};
}

// ---------------------------------------------------------------------------
extern "C" void kernel_launch(void* const* d_in, const int* in_sizes, int n_in,
                              void* d_out, int out_size, void* d_ws, size_t ws_size,
                              hipStream_t stream)
{
    const float* cam_feat = (const float*)d_in[0];
    const float* ego2cam  = (const float*)d_in[1];
    const float* conv_w   = (const float*)d_in[2];
    const float* conv_b   = (const float*)d_in[3];
    const int*   img_h    = (const int*)d_in[4];
    const int*   img_w    = (const int*)d_in[5];
    float* out = (float*)d_out;

    // ws (all bf16 now): camt 17.3MB | feat 40.3MB | wbf 1.5MB | part 29.5MB
    // total ~88.7MB (ws proven >= 112MB in round 1). No aliasing.
    bf16* camt = (bf16*)d_ws;
    bf16* feat = camt + (size_t)NCAM*CH*FH*FW;
    bf16* wbf  = feat + (size_t)FROWS*FCOLS*CINP;
    bf16* part = wbf  + (size_t)9*128*CINP;

    transpose_kernel<<<dim3(6, FH, NCAM), 256, 0, stream>>>(cam_feat, camt);
    wprep_kernel<<<(128*CINP + 255)/256, 256, 0, stream>>>(conv_w, wbf);
    border_kernel<<<724, 128, 0, stream>>>(feat);
    proj_kernel<<<NPIX/4, 256, 0, stream>>>(camt, ego2cam, img_h, img_w, feat);
    conv_mfma_kernel<<<dim3(8, 15, 4), 256, 0, stream>>>(feat, wbf, part);
    combine_kernel<<<(128*NPIX/8 + 255)/256, 256, 0, stream>>>(part, conv_b, out);
}

// Round 7
// 105.535 us; speedup vs baseline: 1.5925x; 1.5925x over previous
//
#include <hip/hip_runtime.h>
#include <hip/hip_bf16.h>

#define BH 120
#define BW 240
#define NLVL 5
#define NCAM 6
#define CH 128
#define FH 64
#define FW 176
#define CIN 655
#define CINP 672            // padded to 21*32
#define NCT 21
#define FROWS 124           // padded rows; 0..121 used, 122..123 slack
#define FCOLS 242
#define NPIX (BH*BW)

typedef __hip_bfloat16 bf16;
typedef __attribute__((ext_vector_type(8))) short s16x8;
typedef __attribute__((ext_vector_type(4))) float f32x4;
typedef unsigned int uint;
typedef __attribute__((ext_vector_type(4), aligned(4))) uint uint4a;

#define G_AS __attribute__((address_space(1)))
#define L_AS __attribute__((address_space(3)))

__device__ __forceinline__ float bf2f(unsigned short u) {
    union { unsigned int i; float f; } c; c.i = ((unsigned int)u) << 16; return c.f;
}
__device__ __forceinline__ uint f2bu(float x) {
    return (uint)__hip_bfloat16_raw(__float2bfloat16(x)).x;
}
__device__ __forceinline__ float blo(uint u) {
    union { uint i; float f; } c; c.i = u << 16; return c.f;
}
__device__ __forceinline__ float bhi(uint u) {
    union { uint i; float f; } c; c.i = u & 0xFFFF0000u; return c.f;
}

// ---------------------------------------------------------------------------
// Kernel T: transpose cam_feat [6][128][64][176] f32 -> camt bf16 [6][64][176][128]
// ---------------------------------------------------------------------------
__global__ __launch_bounds__(256) void transpose_kernel(
    const float* __restrict__ in, bf16* __restrict__ out)
{
    __shared__ float t[32][129];
    int n = blockIdx.z, h = blockIdx.y, w0 = blockIdx.x * 32;
    int wlim = min(32, FW - w0);
    int wx = threadIdx.x & 31, cg = threadIdx.x >> 5;
    if (wx < wlim) {
        #pragma unroll
        for (int k = 0; k < 16; ++k) {
            int c = cg + k * 8;
            t[wx][c] = in[((n*CH + c)*FH + h)*FW + w0 + wx];
        }
    }
    __syncthreads();
    int c2 = threadIdx.x & 127, wi = threadIdx.x >> 7;
    for (int w = wi; w < wlim; w += 2)
        out[((n*FH + h)*FW + w0 + w)*CH + c2] = __float2bfloat16(t[w][c2]);
}

// ---------------------------------------------------------------------------
// Kernel W: conv_w [128][655][3][3] f32 -> wbf [9][128][672] bf16 (tail zero)
// ---------------------------------------------------------------------------
__global__ __launch_bounds__(256) void wprep_kernel(
    const float* __restrict__ w, bf16* __restrict__ wbf)
{
    int idx = blockIdx.x * 256 + threadIdx.x;
    if (idx >= 128 * CINP) return;
    int oc = idx / CINP, cin = idx - oc * CINP;
    float v[9];
    if (cin < CIN) {
        const float* s = w + ((size_t)oc * CIN + cin) * 9;
        #pragma unroll
        for (int k = 0; k < 9; ++k) v[k] = s[k];
    } else {
        #pragma unroll
        for (int k = 0; k < 9; ++k) v[k] = 0.f;
    }
    #pragma unroll
    for (int k = 0; k < 9; ++k)
        wbf[(size_t)(k * 128 + oc) * CINP + cin] = __float2bfloat16(v[k]);
}

// ---------------------------------------------------------------------------
// Kernel Z: zero the 724 border pixels across all 672 cin.
// ---------------------------------------------------------------------------
__global__ __launch_bounds__(128) void border_kernel(bf16* __restrict__ feat)
{
    int b = blockIdx.x;            // 0..723
    int row, col;
    if (b < 242)      { row = 0;   col = b; }
    else if (b < 484) { row = 121; col = b - 242; }
    else if (b < 604) { row = b - 484 + 1; col = 0; }
    else              { row = b - 604 + 1; col = 241; }
    s16x8* p = (s16x8*)(feat + ((size_t)row*FCOLS + col)*CINP);
    int t = threadIdx.x;
    if (t < 84) p[t] = (s16x8){0,0,0,0,0,0,0,0};
}

// ---------------------------------------------------------------------------
// Kernel P v3: 1 wave = 1 BEV pixel; camt bf16 (1 dword = 2ch per tap);
// XCD-swizzled blockIdx for L2-local camt reuse. (unchanged from round 6)
// ---------------------------------------------------------------------------
__global__ __launch_bounds__(256) void proj_kernel(
    const bf16* __restrict__ camt,
    const float* __restrict__ e2c,
    const int* __restrict__ pimgh, const int* __restrict__ pimgw,
    bf16* __restrict__ feat)
{
    __shared__ int   s_soff[4][32];
    __shared__ float s_w4[4][30][4];
    __shared__ int   s_val[4][32];

    const int wv = threadIdx.x >> 6;
    const int lane = threadIdx.x & 63;
    const int bid = blockIdx.x;                      // 7200 blocks
    const int swz = (bid & 7) * 900 + (bid >> 3);    // T1 XCD swizzle
    const int pix = swz * 4 + wv;
    const int bx = pix % BW, by = pix / BW;
    float xw = (float)(-30.0 + bx * (60.0/239.0)); if (bx == BW-1) xw = 30.f;
    float yw = (float)(-15.0 + by * (30.0/119.0)); if (by == BH-1) yw = 15.f;

    const bool act = lane < 30;
    int valid = 0, ix = 0, iy = 0, cam = 0;
    float fx = 0.f, fy = 0.f;
    if (act) {
        int l = lane / 6; cam = lane - l*6;
        float h = -1.f + 0.5f * (float)l;
        const float* M = e2c + cam * 16;
        float cx = M[0]*xw + M[1]*yw + M[2]*h  + M[3];
        float cy = M[4]*xw + M[5]*yw + M[6]*h  + M[7];
        float cz = M[8]*xw + M[9]*yw + M[10]*h + M[11];
        float iw = (float)pimgw[0], ih = (float)pimgh[0];
        float px = ((cx/cz + 1e-9f)/iw - 0.5f) * 2.f;
        float py = ((cy/cz + 1e-9f)/ih - 0.5f) * 2.f;
        valid = (cz > 1e-9f) && (px > -1.f) && (px < 1.f)
                             && (py > -1.f) && (py < 1.f);
        float xs = ((px + 1.f)*(float)FW - 1.f) * 0.5f;
        float ys = ((py + 1.f)*(float)FH - 1.f) * 0.5f;
        float x0 = floorf(xs), y0 = floorf(ys);
        fx = xs - x0; fy = ys - y0;
        ix = (int)x0; iy = (int)y0;
        s_val[wv][lane] = valid;
    }
    __syncthreads();
    if (act) {
        int lbase = (lane / 6) * 6;
        int cnt = s_val[wv][lbase] + s_val[wv][lbase+1] + s_val[wv][lbase+2]
                + s_val[wv][lbase+3] + s_val[wv][lbase+4] + s_val[wv][lbase+5];
        float inv = (cnt > 0) ? (1.f / (float)cnt) : 0.f;
        float sc = valid ? inv : 0.f;
        int bx0 = min(max(ix, 0), FW-2);
        int by0 = min(max(iy, 0), FH-2);
        float gx0 = (1.f - fx) * sc, gx1 = fx * sc;
        float wx0 = 0.f, wx1 = 0.f;
        if (ix >= 0)     { if (ix == bx0) wx0 += gx0; else wx1 += gx0; }
        if (ix+1 <= FW-1){ if (ix+1 == bx0) wx0 += gx1; else wx1 += gx1; }
        float wy0 = 0.f, wy1 = 0.f;
        float gy0 = 1.f - fy, gy1 = fy;
        if (iy >= 0)     { if (iy == by0) wy0 += gy0; else wy1 += gy0; }
        if (iy+1 <= FH-1){ if (iy+1 == by0) wy0 += gy1; else wy1 += gy1; }
        s_w4[wv][lane][0] = wx0 * wy0;
        s_w4[wv][lane][1] = wx0 * wy1;
        s_w4[wv][lane][2] = wx1 * wy0;
        s_w4[wv][lane][3] = wx1 * wy1;
        s_soff[wv][lane] = valid ? ((cam*FH + by0)*FW + bx0)*CH : -1;
    }
    __syncthreads();

    const int c2 = lane * 2;
    float va[NLVL], vb[NLVL];
    #pragma unroll
    for (int l = 0; l < NLVL; ++l) { va[l] = 0.f; vb[l] = 0.f; }

    #pragma unroll
    for (int l = 0; l < NLVL; ++l) {
        #pragma unroll
        for (int cm = 0; cm < NCAM; ++cm) {
            int id = l*6 + cm;
            int so = s_soff[wv][id];
            if (so >= 0) {                       // wave-uniform branch
                const bf16* bp = camt + so + c2;
                uint q0 = *(const uint*)(bp);
                uint q2 = *(const uint*)(bp + CH);
                uint q1 = *(const uint*)(bp + FW*CH);
                uint q3 = *(const uint*)(bp + FW*CH + CH);
                float w0 = s_w4[wv][id][0], w1 = s_w4[wv][id][1];
                float w2 = s_w4[wv][id][2], w3 = s_w4[wv][id][3];
                va[l] += w0*blo(q0) + w1*blo(q1) + w2*blo(q2) + w3*blo(q3);
                vb[l] += w0*bhi(q0) + w1*bhi(q1) + w2*bhi(q2) + w3*bhi(q3);
            }
        }
    }

    bf16* dpix = feat + ((size_t)(by+1)*FCOLS + (bx+1))*CINP;
    uint u0 = f2bu(va[0]) | (f2bu(va[1]) << 16);
    uint u1 = f2bu(va[2]) | (f2bu(va[3]) << 16);
    uint u2 = f2bu(va[4]) | (f2bu(vb[0]) << 16);
    uint u3 = f2bu(vb[1]) | (f2bu(vb[2]) << 16);
    uint u4 = f2bu(vb[3]) | (f2bu(vb[4]) << 16);
    char* dst = (char*)(dpix + c2*5);
    *(uint4a*)dst = (uint4a){u0, u1, u2, u3};
    *(uint*)(dst + 16) = u4;
    if (lane < 15) {
        int j = lane / 5, l = lane - j*5;
        float v = (j == 0) ? xw : (j == 1) ? yw : (-1.f + 0.5f*(float)l);
        dpix[CH*5 + lane] = __float2bfloat16(v);
    }
}

// ---------------------------------------------------------------------------
// Kernel C v3: implicit-GEMM conv, K-split x4. Block = 128oc x (8x32)px,
// 4 waves, wave = 128oc x 64px (m=8, f=4). Weights AND halo both staged in
// LDS via global_load_lds (round-5 proven paths; round-6's register-A
// double-buffer spilled: 256+ VGPR under the (256,2) cap -> 84MB scratch).
// Regs: acc 128 (AGPR) + A 32 + B 4 + addr ~30 -> no spill, 2 blocks/CU.
// Per wave-phase: 12 ds_read_b128 (~144cy) vs 32 MFMA (~155cy) -> balanced.
// LDS 60KB: halo 2x22528 + W 2x8192; 2 blocks/CU = 120KB < 160KB.
// ---------------------------------------------------------------------------
__global__ __launch_bounds__(256, 2) void conv_mfma_kernel(
    const bf16* __restrict__ feat,     // [124][242][672]
    const bf16* __restrict__ wbf,      // [9][128][672]
    bf16* __restrict__ part)           // [4][128][28800]
{
    __shared__ __align__(16) char lds[61440];
    const int tid  = threadIdx.x;
    const int wv   = tid >> 6;
    const int lane = tid & 63;
    const int t15  = tid & 15;
    const int kgl  = (tid >> 4) & 3;
    const int y0p = blockIdx.y * 8;        // 15 row-tiles
    const int x0p = blockIdx.x * 32;       // 8 col-tiles (last clamped)
    const int q   = blockIdx.z;
    const int ct0 = q ? (1 + 5*q) : 0;     // 0,6,11,16
    const int nct = q ? 5 : 6;
    const int nph = nct * 9;

    const int HB0 = 0, HB1 = 22528, WB0 = 45056, WB1 = 53248;

    f32x4 acc[8][4];
    #pragma unroll
    for (int m = 0; m < 8; ++m)
        #pragma unroll
        for (int f = 0; f < 4; ++f)
            acc[m][f] = (f32x4){0.f, 0.f, 0.f, 0.f};

    auto stageW = [&](int ct, int off, int wb) {
        #pragma unroll
        for (int jj = 0; jj < 2; ++jj) {
            int j = 2*wv + jj;                   // 8 wave-issues
            int cch = j*64 + lane;
            int oc = cch >> 2, kgp = cch & 3;
            int kg = kgp ^ ((oc >> 1) & 3);      // source-side swizzle
            const bf16* src = wbf + ((size_t)(off*128 + oc)*CINP + ct*32 + kg*8);
            __builtin_amdgcn_global_load_lds((const G_AS void*)src,
                                             (L_AS void*)(lds + wb + j*1024),
                                             16, 0, 0);
        }
    };
    // 10x34-px halo (rounded to 352 px; rows y0p..y0p+10 <= 122 < FROWS)
    auto stageH = [&](int ct, int hb) {
        for (int j = wv; j < 22; j += 4) {
            int cch = j*64 + lane;
            int pp = cch >> 2, kgp = cch & 3;
            int kg = kgp ^ ((pp >> 1) & 3);
            int row = pp / 34;
            int col = pp - row*34;
            int gc = min(x0p + col, FCOLS-1);    // col clamp for last tile
            const bf16* src = feat + ((size_t)(y0p + row)*FCOLS + gc)*CINP
                                   + ct*32 + kg*8;
            __builtin_amdgcn_global_load_lds((const G_AS void*)src,
                                             (L_AS void*)(lds + hb + j*1024),
                                             16, 0, 0);
        }
    };

    stageH(ct0, HB0);
    stageW(ct0, 0, WB0);
    __syncthreads();

    int lct = 0, off = 0;
    for (int p = 0; p < nph; ++p) {
        if (p + 1 < nph) {
            int off1 = off + 1, lct1 = lct;
            if (off1 == 9) { off1 = 0; ++lct1; }
            stageW(ct0 + lct1, off1, ((p+1) & 1) ? WB1 : WB0);
            if (off1 == 0) stageH(ct0 + lct1, (lct1 & 1) ? HB1 : HB0);
        }
        const int wb = (p & 1) ? WB1 : WB0;
        const int hb = (lct & 1) ? HB1 : HB0;
        const int ky = off / 3, kx = off - ky*3;

        s16x8 A[8];
        #pragma unroll
        for (int m = 0; m < 8; ++m) {
            int oc = m*16 + t15;
            A[m] = *(const s16x8*)(lds + wb + oc*64 + ((kgl ^ ((oc>>1)&3)) << 4));
        }
        #pragma unroll
        for (int f = 0; f < 4; ++f) {
            const int fr = f >> 1, fc = f & 1;
            int hp = (2*wv + fr + ky)*34 + fc*16 + t15 + kx;
            s16x8 Bv = *(const s16x8*)(lds + hb + hp*64
                                       + ((kgl ^ ((hp>>1)&3)) << 4));
            __builtin_amdgcn_s_setprio(1);
            #pragma unroll
            for (int m = 0; m < 8; ++m)
                acc[m][f] = __builtin_amdgcn_mfma_f32_16x16x32_bf16(
                                A[m], Bv, acc[m][f], 0, 0, 0);
            __builtin_amdgcn_s_setprio(0);
        }
        __syncthreads();
        if (++off == 9) { off = 0; ++lct; }
    }

    bf16* pq = part + (size_t)q * (128*NPIX);
    #pragma unroll
    for (int f = 0; f < 4; ++f) {
        const int fr = f >> 1, fc = f & 1;
        const int x = x0p + fc*16 + t15;
        if (x < BW) {
            const int y = y0p + 2*wv + fr;
            #pragma unroll
            for (int m = 0; m < 8; ++m) {
                #pragma unroll
                for (int r = 0; r < 4; ++r) {
                    int oc = m*16 + kgl*4 + r;   // D: row=(lane>>4)*4+r
                    pq[(size_t)oc*NPIX + y*BW + x] = __float2bfloat16(acc[m][f][r]);
                }
            }
        }
    }
}

// ---------------------------------------------------------------------------
// Kernel R: out[oc][pix] = sum_q part[q][oc][pix] + bias[oc]
// ---------------------------------------------------------------------------
__global__ __launch_bounds__(256) void combine_kernel(
    const bf16* __restrict__ part, const float* __restrict__ bias,
    float* __restrict__ out)
{
    int i8 = blockIdx.x * 256 + threadIdx.x;
    if (i8 >= 128*NPIX/8) return;
    int oc = i8 / (NPIX/8);
    float s[8];
    float b = bias[oc];
    #pragma unroll
    for (int k = 0; k < 8; ++k) s[k] = b;
    #pragma unroll
    for (int qq = 0; qq < 4; ++qq) {
        s16x8 v = *(const s16x8*)(part + (size_t)qq*(128*NPIX) + (size_t)i8*8);
        #pragma unroll
        for (int k = 0; k < 8; ++k) s[k] += bf2f((unsigned short)v[k]);
    }
    f32x4* o = (f32x4*)(out + (size_t)i8*8);
    o[0] = (f32x4){s[0], s[1], s[2], s[3]};
    o[1] = (f32x4){s[4], s[5], s[6], s[7]};
}

// ---------------------------------------------------------------------------
extern "C" void kernel_launch(void* const* d_in, const int* in_sizes, int n_in,
                              void* d_out, int out_size, void* d_ws, size_t ws_size,
                              hipStream_t stream)
{
    const float* cam_feat = (const float*)d_in[0];
    const float* ego2cam  = (const float*)d_in[1];
    const float* conv_w   = (const float*)d_in[2];
    const float* conv_b   = (const float*)d_in[3];
    const int*   img_h    = (const int*)d_in[4];
    const int*   img_w    = (const int*)d_in[5];
    float* out = (float*)d_out;

    // ws (all bf16): camt 17.3MB | feat 40.3MB | wbf 1.5MB | part 29.5MB
    bf16* camt = (bf16*)d_ws;
    bf16* feat = camt + (size_t)NCAM*CH*FH*FW;
    bf16* wbf  = feat + (size_t)FROWS*FCOLS*CINP;
    bf16* part = wbf  + (size_t)9*128*CINP;

    transpose_kernel<<<dim3(6, FH, NCAM), 256, 0, stream>>>(cam_feat, camt);
    wprep_kernel<<<(128*CINP + 255)/256, 256, 0, stream>>>(conv_w, wbf);
    border_kernel<<<724, 128, 0, stream>>>(feat);
    proj_kernel<<<NPIX/4, 256, 0, stream>>>(camt, ego2cam, img_h, img_w, feat);
    conv_mfma_kernel<<<dim3(8, 15, 4), 256, 0, stream>>>(feat, wbf, part);
    combine_kernel<<<(128*NPIX/8 + 255)/256, 256, 0, stream>>>(part, conv_b, out);
}